// Round 4
// baseline (236.994 us; speedup 1.0000x reference)
//
#include <hip/hip_runtime.h>
#include <hip/hip_bf16.h>
#include <hip/hip_fp16.h>
#include <cstdint>

#define NT      32768
#define DIN     256
#define DHID    1024
#define DOUT    256
#define NPLANES 8
#define NBLK    (NT / 256)
#define MTILE   128

typedef unsigned short u16;
typedef __attribute__((ext_vector_type(8))) _Float16 f16x8;
typedef __attribute__((ext_vector_type(4))) float    f32x4;

// ---------------- workspace layout (bytes) ----------------
#define WS_OFFSETS  0
#define WS_META     64
#define WS_TILEP    512
#define WS_TILEM    2048
#define WS_BLKHIST  4096
#define WS_BLKBASE  (WS_BLKHIST + NBLK*8*4)
#define WS_PERM     (WS_BLKBASE + NBLK*8*4)
#define WS_XB       (WS_PERM + NT*4)              // NT*DIN f16, bucketed order
#define WS_W1B      (WS_XB  + NT*DIN*2)           // L*DHID*DIN f16
#define WS_W2B      (WS_W1B + NPLANES*DHID*DIN*2) // L*DOUT*DHID f16

__device__ __forceinline__ u16 f2h_bits(float f) {
    __half h = __float2half(f);
    return *reinterpret_cast<u16*>(&h);
}

__device__ __forceinline__ void gl_lds16(const void* g, void* l) {
    __builtin_amdgcn_global_load_lds(
        (const __attribute__((address_space(1))) void*)g,
        (__attribute__((address_space(3))) void*)l,
        16, 0, 0);
}

// ---------------- bucketing (atomic-free, deterministic) ----------------
__global__ void hist_k(const int* __restrict__ pidx, int* __restrict__ blkhist) {
    __shared__ int cnt[NPLANES];
    const int t = threadIdx.x, lane = t & 63;
    if (t < NPLANES) cnt[t] = 0;
    __syncthreads();
    const int p = pidx[blockIdx.x * 256 + t];
#pragma unroll
    for (int q = 0; q < NPLANES; ++q) {
        unsigned long long m = __ballot(p == q);
        if (p == q && __popcll(m & ((1ULL << lane) - 1)) == 0)
            atomicAdd(&cnt[q], __popcll(m));
    }
    __syncthreads();
    if (t < NPLANES) blkhist[blockIdx.x * NPLANES + t] = cnt[t];
}

__global__ void scan_k(const int* __restrict__ blkhist, int* __restrict__ offsets,
                       int* __restrict__ blkbase, int* __restrict__ meta,
                       int* __restrict__ tileP, int* __restrict__ tileM) {
    __shared__ int tot[NPLANES];
    const int t = threadIdx.x;
    if (t < NPLANES) {
        int s = 0;
#pragma unroll 8
        for (int b = 0; b < NBLK; ++b) s += blkhist[b * NPLANES + t];
        tot[t] = s;
    }
    __syncthreads();
    if (t == 0) {
        int off = 0, tc = 0;
        for (int p = 0; p < NPLANES; ++p) {
            offsets[p] = off;
            for (int m = 0; m < tot[p]; m += MTILE) { tileP[tc] = p; tileM[tc] = m; ++tc; }
            off += tot[p];
        }
        offsets[NPLANES] = off;
        meta[0] = tc;
    }
    __syncthreads();
    if (t < NPLANES) {
        int run = offsets[t];
#pragma unroll 8
        for (int b = 0; b < NBLK; ++b) {
            blkbase[b * NPLANES + t] = run;
            run += blkhist[b * NPLANES + t];
        }
    }
}

__global__ void scatter_k(const int* __restrict__ pidx, const int* __restrict__ blkbase,
                          int* __restrict__ perm) {
    __shared__ int wcnt[4][NPLANES];
    __shared__ int wbase[4][NPLANES];
    const int t = threadIdx.x, lane = t & 63, wave = t >> 6;
    const int i = blockIdx.x * 256 + t;
    const int p = pidx[i];
    int rank = 0;
#pragma unroll
    for (int q = 0; q < NPLANES; ++q) {
        unsigned long long m = __ballot(p == q);
        if (lane == 0) wcnt[wave][q] = __popcll(m);
        if (p == q) rank = __popcll(m & ((1ULL << lane) - 1));
    }
    __syncthreads();
    if (t < NPLANES) {
        int run = blkbase[blockIdx.x * NPLANES + t];
#pragma unroll
        for (int w = 0; w < 4; ++w) { wbase[w][t] = run; run += wcnt[w][t]; }
    }
    __syncthreads();
    perm[wbase[wave][p] + rank] = i;
}

// ---------------- converts ----------------
__global__ void cvtx_k(const float* __restrict__ x, const int* __restrict__ perm,
                       u16* __restrict__ xb) {
    const int n4 = NT * DIN / 4;
    const int stride = gridDim.x * blockDim.x;
    for (int i = blockIdx.x * blockDim.x + threadIdx.x; i < n4; i += stride) {
        const int row = i >> 6;
        const int c4  = i & 63;
        const int src = perm[row];
        float4 v = reinterpret_cast<const float4*>(x)[src * 64 + c4];
        ushort4 o;
        o.x = f2h_bits(v.x); o.y = f2h_bits(v.y);
        o.z = f2h_bits(v.z); o.w = f2h_bits(v.w);
        reinterpret_cast<ushort4*>(xb)[i] = o;
    }
}

__global__ void cvtw_k(const float* __restrict__ W1, const float* __restrict__ W2,
                       u16* __restrict__ w1b, u16* __restrict__ w2b) {
    const int n1 = NPLANES * DHID * DIN / 4;
    const int n2 = NPLANES * DOUT * DHID / 4;
    const int stride = gridDim.x * blockDim.x;
    for (int i = blockIdx.x * blockDim.x + threadIdx.x; i < n1 + n2; i += stride) {
        const float4* s; ushort4* d; int j;
        if (i < n1) { s = (const float4*)W1; d = (ushort4*)w1b; j = i; }
        else        { s = (const float4*)W2; d = (ushort4*)w2b; j = i - n1; }
        float4 v = s[j];
        ushort4 o;
        o.x = f2h_bits(v.x); o.y = f2h_bits(v.y);
        o.z = f2h_bits(v.z); o.w = f2h_bits(v.w);
        d[j] = o;
    }
}

// ---------------- fused 2-layer MLP kernel ----------------
// Block = 128 tokens of one plane. 8 waves (2 token-halves x 4 col-quads).
// LDS: buf0 [sA 8KB | sW 16KB] @0, buf1 @24KB, sH 64KB @48KB. Total 112KB.
// All staged tiles: [R rows][32 K] f16, rows of 4x16B chunks, chunk^=(row&3).
// sH: [128 tok][256 hid] f16, 32 chunks/row, chunk^=(row&7).
__global__ __launch_bounds__(512, 2) void fused_k(
    const u16* __restrict__ xb, const u16* __restrict__ w1b,
    const u16* __restrict__ w2b, const float* __restrict__ b1,
    const float* __restrict__ b2, const int* __restrict__ perm,
    const int* __restrict__ offsets, const int* __restrict__ meta,
    const int* __restrict__ tileP, const int* __restrict__ tileM,
    float* __restrict__ out)
{
    extern __shared__ __align__(16) char smem[];
    const int nwg  = meta[0];
    const int orig = blockIdx.x;
    if (orig >= nwg) return;
    // bijective XCD-chunked swizzle (m204): XCD x gets a contiguous tile range
    const int q = nwg >> 3, r = nwg & 7;
    const int xcd = orig & 7, jj = orig >> 3;
    const int tile = (xcd < r ? xcd * (q + 1) : r * (q + 1) + (xcd - r) * q) + jj;
    const int p   = tileP[tile];
    const int m0  = tileM[tile];
    const int off = offsets[p];
    const int cnt = offsets[p + 1] - off;

    const int tid  = threadIdx.x;
    const int wave = tid >> 6, lane = tid & 63;
    const int wr = wave >> 2, wc = wave & 3;   // 2 x 4 wave grid
    const int lm = lane & 15, lk = lane >> 4;

    u16* const sBuf0 = (u16*)smem;
    u16* const sBuf1 = (u16*)(smem + 24576);
    u16* const sH    = (u16*)(smem + 49152);

    // ---- staging sources (per-lane global addr carries the swizzle) ----
    const int arow = tid >> 2, ac = tid & 3;                 // A slot: 128 rows x 4 chunks
    const u16* aS = xb + (size_t)(off + min(m0 + arow, cnt - 1)) * DIN
                       + ((ac ^ (arow & 3)) * 8);
    const int w0row = tid >> 2,         w0c = tid & 3;       // W slots: 256 rows x 4 chunks
    const int w1row = (512 + tid) >> 2, w1c = (512 + tid) & 3;
    const u16* w1S0 = w1b + ((size_t)p * DHID + w0row) * DIN + ((w0c ^ (w0row & 3)) * 8);
    const u16* w1S1 = w1b + ((size_t)p * DHID + w1row) * DIN + ((w1c ^ (w1row & 3)) * 8);
    const u16* w2S0 = w2b + ((size_t)p * DOUT + w0row) * DHID + ((w0c ^ (w0row & 3)) * 8);
    const u16* w2S1 = w2b + ((size_t)p * DOUT + w1row) * DHID + ((w1c ^ (w1row & 3)) * 8);
    // LDS dest (u16 units): gl_lds dest = wave-uniform base + lane*16B
    const int dA  = tid * 8;
    const int dW0 = 4096 + tid * 8;
    const int dW1 = 8192 + tid * 8;

    // ---- fragment read offsets (u16 units) ----
    int rdA[4], rdB[4], rdH[4];
#pragma unroll
    for (int mf = 0; mf < 4; ++mf)
        rdA[mf] = (wr * 64 + mf * 16 + lm) * 32 + ((lk ^ (lm & 3)) * 8);
#pragma unroll
    for (int nf = 0; nf < 4; ++nf)
        rdB[nf] = 4096 + (wc * 64 + nf * 16 + lm) * 32 + ((lk ^ (lm & 3)) * 8);
#pragma unroll
    for (int mf = 0; mf < 4; ++mf)
        rdH[mf] = (wr * 64 + mf * 16 + lm) * 256;   // + swizzled chunk at use

    f32x4 acc2[4][4];
#pragma unroll
    for (int a = 0; a < 4; ++a)
#pragma unroll
        for (int b = 0; b < 4; ++b) acc2[a][b] = (f32x4){0.f, 0.f, 0.f, 0.f};

#define STAGE_A(buf, ks)       gl_lds16(aS + (ks) * 32, (buf) + dA)
#define STAGE_W1(buf, ch, ks)  do { \
        gl_lds16(w1S0 + (size_t)(ch) * 65536 + (ks) * 32, (buf) + dW0); \
        gl_lds16(w1S1 + (size_t)(ch) * 65536 + (ks) * 32, (buf) + dW1); } while (0)
#define STAGE_W2(buf, ch, ks)  do { \
        gl_lds16(w2S0 + (ch) * 256 + (ks) * 32, (buf) + dW0); \
        gl_lds16(w2S1 + (ch) * 256 + (ks) * 32, (buf) + dW1); } while (0)

    // prologue
    STAGE_A(sBuf0, 0); STAGE_W1(sBuf0, 0, 0);
    __syncthreads();

    for (int ch = 0; ch < 4; ++ch) {
        f32x4 acc1[4][4];
#pragma unroll
        for (int a = 0; a < 4; ++a)
#pragma unroll
            for (int b = 0; b < 4; ++b) acc1[a][b] = (f32x4){0.f, 0.f, 0.f, 0.f};

        // ---- layer-1: h[128 tok][256 hid-chunk] over K=256 in 8 steps ----
#pragma unroll
        for (int ks = 0; ks < 8; ++ks) {
            u16* const bc = (ks & 1) ? sBuf1 : sBuf0;
            u16* const nb = (ks & 1) ? sBuf0 : sBuf1;
            if (ks < 7) { STAGE_A(nb, ks + 1); STAGE_W1(nb, ch, ks + 1); }
            else        { STAGE_W2(nb, ch, 0); }
            f16x8 af[4], bf[4];
#pragma unroll
            for (int mf = 0; mf < 4; ++mf) af[mf] = *(const f16x8*)(bc + rdA[mf]);
#pragma unroll
            for (int nf = 0; nf < 4; ++nf) bf[nf] = *(const f16x8*)(bc + rdB[nf]);
#pragma unroll
            for (int mf = 0; mf < 4; ++mf)
#pragma unroll
                for (int nf = 0; nf < 4; ++nf)
                    acc1[mf][nf] = __builtin_amdgcn_mfma_f32_16x16x32_f16(
                        af[mf], bf[nf], acc1[mf][nf], 0, 0, 0);
            __syncthreads();
        }

        // ---- gelu + write h chunk to sH (swizzled) ----
#pragma unroll
        for (int nf = 0; nf < 4; ++nf) {
            const float bb = b1[p * DHID + ch * 256 + wc * 64 + nf * 16 + lm];
            const int hc = wc * 8 + nf * 2 + (lm >> 3);   // 16B-chunk index 0..31
#pragma unroll
            for (int mf = 0; mf < 4; ++mf) {
#pragma unroll
                for (int j2 = 0; j2 < 4; ++j2) {
                    const int tok = wr * 64 + mf * 16 + lk * 4 + j2;
                    float v = acc1[mf][nf][j2] + bb;
                    float g = 0.5f * v * (1.0f + erff(v * 0.70710678118654752f));
                    sH[tok * 256 + ((hc ^ (tok & 7)) * 8) + (lm & 7)] = f2h_bits(g);
                }
            }
        }
        __syncthreads();   // sH visible to all waves (W2 step0 already staged+drained)

        // ---- layer-2 partial: out += h_chunk x W2[:, chunk]^T, 8 steps ----
#pragma unroll
        for (int ks = 0; ks < 8; ++ks) {
            u16* const bc = (ks & 1) ? sBuf1 : sBuf0;
            u16* const nb = (ks & 1) ? sBuf0 : sBuf1;
            if (ks < 7)      STAGE_W2(nb, ch, ks + 1);
            else if (ch < 3) { STAGE_A(nb, 0); STAGE_W1(nb, ch + 1, 0); }
            f16x8 af[4], bf[4];
#pragma unroll
            for (int mf = 0; mf < 4; ++mf)
                af[mf] = *(const f16x8*)(sH + rdH[mf] + (((ks * 4 + lk) ^ (lm & 7)) * 8));
#pragma unroll
            for (int nf = 0; nf < 4; ++nf) bf[nf] = *(const f16x8*)(bc + rdB[nf]);
#pragma unroll
            for (int mf = 0; mf < 4; ++mf)
#pragma unroll
                for (int nf = 0; nf < 4; ++nf)
                    acc2[mf][nf] = __builtin_amdgcn_mfma_f32_16x16x32_f16(
                        af[mf], bf[nf], acc2[mf][nf], 0, 0, 0);
            __syncthreads();
        }
    }

    // ---- epilogue: bias + scatter rows via perm (f32, 64B runs) ----
#pragma unroll
    for (int nf = 0; nf < 4; ++nf) {
        const int oc = wc * 64 + nf * 16 + lm;
        const float bb = b2[p * DOUT + oc];
#pragma unroll
        for (int mf = 0; mf < 4; ++mf) {
#pragma unroll
            for (int j2 = 0; j2 < 4; ++j2) {
                const int tok = wr * 64 + mf * 16 + lk * 4 + j2;
                if (m0 + tok < cnt)
                    out[(size_t)perm[off + m0 + tok] * DOUT + oc] = acc2[mf][nf][j2] + bb;
            }
        }
    }
#undef STAGE_A
#undef STAGE_W1
#undef STAGE_W2
}

// ---------------- launch ----------------
extern "C" void kernel_launch(void* const* d_in, const int* in_sizes, int n_in,
                              void* d_out, int out_size, void* d_ws, size_t ws_size,
                              hipStream_t stream) {
    const float* x    = (const float*)d_in[0];
    const float* W1   = (const float*)d_in[1];
    const float* b1   = (const float*)d_in[2];
    const float* W2   = (const float*)d_in[3];
    const float* b2   = (const float*)d_in[4];
    const int*   pidx = (const int*)d_in[5];
    float*       out  = (float*)d_out;

    char* ws      = (char*)d_ws;
    int* offsets  = (int*)(ws + WS_OFFSETS);
    int* meta     = (int*)(ws + WS_META);
    int* tileP    = (int*)(ws + WS_TILEP);
    int* tileM    = (int*)(ws + WS_TILEM);
    int* blkhist  = (int*)(ws + WS_BLKHIST);
    int* blkbase  = (int*)(ws + WS_BLKBASE);
    int* perm     = (int*)(ws + WS_PERM);
    u16* xb       = (u16*)(ws + WS_XB);
    u16* w1b      = (u16*)(ws + WS_W1B);
    u16* w2b      = (u16*)(ws + WS_W2B);

    // opt-in for 112KB dynamic LDS (idempotent; ignore error if unsupported)
    (void)hipFuncSetAttribute((const void*)fused_k,
                              hipFuncAttributeMaxDynamicSharedMemorySize, 114688);

    hist_k<<<NBLK, 256, 0, stream>>>(pidx, blkhist);
    scan_k<<<1, 64, 0, stream>>>(blkhist, offsets, blkbase, meta, tileP, tileM);
    scatter_k<<<NBLK, 256, 0, stream>>>(pidx, blkbase, perm);

    cvtw_k<<<2048, 256, 0, stream>>>(W1, W2, w1b, w2b);
    cvtx_k<<<2048, 256, 0, stream>>>(x, perm, xb);

    fused_k<<<264, 512, 114688, stream>>>(xb, w1b, w2b, b1, b2, perm,
                                          offsets, meta, tileP, tileM, out);
}

// Round 5
// 132.107 us; speedup vs baseline: 1.7940x; 1.7940x over previous
//
#include <hip/hip_runtime.h>
#include <hip/hip_fp16.h>
#include <cstdint>

#define NT      32768
#define DIN     256
#define DHID    1024
#define DOUT    256
#define NPLANES 8
#define NBLK    (NT / 256)

typedef unsigned short u16;
typedef __attribute__((ext_vector_type(8))) _Float16 f16x8;
typedef __attribute__((ext_vector_type(4))) float    f32x4;

// ---------------- workspace layout (bytes) ----------------
#define WS_OFFSETS 0                           // 9 ints
#define WS_META    64                          // 2 ints (ntiles1, ntiles2)
#define WS_T1P     1024                        // 272 ints
#define WS_T1M     (WS_T1P + 272*4)
#define WS_T2P     (WS_T1M + 272*4)            // 544 ints
#define WS_T2M     (WS_T2P + 544*4)
#define WS_BLKHIST (WS_T2M + 544*4)
#define WS_BLKBASE (WS_BLKHIST + NBLK*8*4)
#define WS_PERM    (WS_BLKBASE + NBLK*8*4)
#define WS_XB      (WS_PERM + NT*4)            // NT*DIN f16, natural order
#define WS_W1B     (WS_XB + NT*DIN*2)
#define WS_W2B     (WS_W1B + NPLANES*DHID*DIN*2)
#define WS_HB      (WS_W2B + NPLANES*DOUT*DHID*2)   // NT*DHID f16, bucketed

__device__ __forceinline__ u16 f2h_bits(float f) {
    __half h = __float2half(f);
    return *reinterpret_cast<u16*>(&h);
}

__device__ __forceinline__ void gl_lds16(const void* g, void* l) {
    __builtin_amdgcn_global_load_lds(
        (const __attribute__((address_space(1))) void*)g,
        (__attribute__((address_space(3))) void*)l,
        16, 0, 0);
}

// ---------------- fused prologue: per-block hist + f32->f16 converts ----------
__global__ void prep_k(const int* __restrict__ pidx, const float* __restrict__ x,
                       const float* __restrict__ W1, const float* __restrict__ W2,
                       int* __restrict__ blkhist, u16* __restrict__ xb,
                       u16* __restrict__ w1b, u16* __restrict__ w2b) {
    __shared__ int cnt[NPLANES];
    const int t = threadIdx.x, lane = t & 63;
    if ((int)blockIdx.x < NBLK) {
        if (t < NPLANES) cnt[t] = 0;
        __syncthreads();
        const int p = pidx[blockIdx.x * 256 + t];
#pragma unroll
        for (int q = 0; q < NPLANES; ++q) {
            unsigned long long m = __ballot(p == q);
            if (p == q && __popcll(m & ((1ULL << lane) - 1)) == 0)
                atomicAdd(&cnt[q], __popcll(m));
        }
        __syncthreads();
        if (t < NPLANES) blkhist[blockIdx.x * NPLANES + t] = cnt[t];
    }
    const int n0 = NT * DIN / 4, n1 = NPLANES * DHID * DIN / 4, n2 = NPLANES * DOUT * DHID / 4;
    const int stride = gridDim.x * blockDim.x;
    for (int i = blockIdx.x * blockDim.x + t; i < n0 + n1 + n2; i += stride) {
        const float4* s; ushort4* d; int j;
        if (i < n0)           { s = (const float4*)x;  d = (ushort4*)xb;  j = i; }
        else if (i < n0 + n1) { s = (const float4*)W1; d = (ushort4*)w1b; j = i - n0; }
        else                  { s = (const float4*)W2; d = (ushort4*)w2b; j = i - n0 - n1; }
        float4 v = s[j];
        ushort4 o;
        o.x = f2h_bits(v.x); o.y = f2h_bits(v.y);
        o.z = f2h_bits(v.z); o.w = f2h_bits(v.w);
        d[j] = o;
    }
}

// ---------------- scan: offsets + two tile lists + per-block bases ----------
__global__ void scan_k(const int* __restrict__ blkhist, int* __restrict__ offsets,
                       int* __restrict__ blkbase, int* __restrict__ meta,
                       int* __restrict__ t1p, int* __restrict__ t1m,
                       int* __restrict__ t2p, int* __restrict__ t2m) {
    __shared__ int tot[NPLANES];
    const int t = threadIdx.x;
    if (t < NPLANES) {
        int s = 0;
#pragma unroll 8
        for (int b = 0; b < NBLK; ++b) s += blkhist[b * NPLANES + t];
        tot[t] = s;
    }
    __syncthreads();
    if (t == 0) {
        int off = 0, tc1 = 0, tc2 = 0;
        for (int p = 0; p < NPLANES; ++p) {
            offsets[p] = off;
            for (int m = 0; m < tot[p]; m += 128) { t1p[tc1] = p; t1m[tc1] = m; ++tc1; }
            for (int m = 0; m < tot[p]; m += 64)  { t2p[tc2] = p; t2m[tc2] = m; ++tc2; }
            off += tot[p];
        }
        offsets[NPLANES] = off;
        meta[0] = tc1; meta[1] = tc2;
    }
    __syncthreads();
    if (t < NPLANES) {
        int run = offsets[t];
#pragma unroll 8
        for (int b = 0; b < NBLK; ++b) {
            blkbase[b * NPLANES + t] = run;
            run += blkhist[b * NPLANES + t];
        }
    }
}

__global__ void scatter_k(const int* __restrict__ pidx, const int* __restrict__ blkbase,
                          int* __restrict__ perm) {
    __shared__ int wcnt[4][NPLANES];
    __shared__ int wbase[4][NPLANES];
    const int t = threadIdx.x, lane = t & 63, wave = t >> 6;
    const int i = blockIdx.x * 256 + t;
    const int p = pidx[i];
    int rank = 0;
#pragma unroll
    for (int q = 0; q < NPLANES; ++q) {
        unsigned long long m = __ballot(p == q);
        if (lane == 0) wcnt[wave][q] = __popcll(m);
        if (p == q) rank = __popcll(m & ((1ULL << lane) - 1));
    }
    __syncthreads();
    if (t < NPLANES) {
        int run = blkbase[blockIdx.x * NPLANES + t];
#pragma unroll
        for (int w = 0; w < 4; ++w) { wbase[w][t] = run; run += wcnt[w][t]; }
    }
    __syncthreads();
    perm[wbase[wave][p] + rank] = i;
}

// ---------------- gemm1: 128x128 tile, A gathered via perm, LDS-staged epilogue
__global__ __launch_bounds__(256, 4) void gemm1_k(
    const u16* __restrict__ xb, const u16* __restrict__ w1b,
    const float* __restrict__ b1, const int* __restrict__ perm,
    const int* __restrict__ offsets, const int* __restrict__ meta,
    const int* __restrict__ t1p, const int* __restrict__ t1m,
    u16* __restrict__ hb)
{
    __shared__ __align__(16) u16 smem[16384];   // sA 16KB | sB 16KB; reused as sOut 32KB
    if ((int)blockIdx.y >= meta[0]) return;
    const int p   = t1p[blockIdx.y];
    const int m0  = t1m[blockIdx.y];
    const int off = offsets[p];
    const int cnt = offsets[p + 1] - off;
    const int n0v = blockIdx.x * 128;

    u16* const sA = smem;
    u16* const sB = smem + 8192;

    const int tid = threadIdx.x, srow = tid >> 3, sch = tid & 7;
    const u16* aptr[4];
    const u16* bptr[4];
#pragma unroll
    for (int i = 0; i < 4; ++i) {
        const int r  = i * 32 + srow;
        const int gr = min(m0 + r, cnt - 1);
        aptr[i] = xb + (size_t)perm[off + gr] * DIN + ((sch ^ (r & 7)) * 8);
        bptr[i] = w1b + ((size_t)p * DHID + n0v + r) * DIN + ((sch ^ (r & 7)) * 8);
    }
    const int wave = tid >> 6, lane = tid & 63;
    const int wm = (wave >> 1) * 64, wn = (wave & 1) * 64;
    const int lm = lane & 15, lk = lane >> 4;

    f32x4 acc[4][4];
#pragma unroll
    for (int a = 0; a < 4; ++a)
#pragma unroll
        for (int b = 0; b < 4; ++b) acc[a][b] = (f32x4){0.f, 0.f, 0.f, 0.f};

    for (int kt = 0; kt < DIN / 64; ++kt) {
        const int k0 = kt * 64;
#pragma unroll
        for (int i = 0; i < 4; ++i) {
            gl_lds16(aptr[i] + k0, sA + i * 2048 + tid * 8);
            gl_lds16(bptr[i] + k0, sB + i * 2048 + tid * 8);
        }
        __syncthreads();
#pragma unroll
        for (int kk = 0; kk < 2; ++kk) {
            f16x8 af[4], bf[4];
#pragma unroll
            for (int mf = 0; mf < 4; ++mf) {
                const int row = wm + mf * 16 + lm;
                const int g   = kk * 4 + lk;
                af[mf] = *(const f16x8*)(sA + row * 64 + ((g ^ (row & 7)) * 8));
            }
#pragma unroll
            for (int nf = 0; nf < 4; ++nf) {
                const int row = wn + nf * 16 + lm;
                const int g   = kk * 4 + lk;
                bf[nf] = *(const f16x8*)(sB + row * 64 + ((g ^ (row & 7)) * 8));
            }
#pragma unroll
            for (int mf = 0; mf < 4; ++mf)
#pragma unroll
                for (int nf = 0; nf < 4; ++nf)
                    acc[mf][nf] = __builtin_amdgcn_mfma_f32_16x16x32_f16(
                        af[mf], bf[nf], acc[mf][nf], 0, 0, 0);
        }
        __syncthreads();
    }

    // ---- epilogue: gelu -> chunk-swizzled sOut (32KB, reuses sA+sB) ----
    // sOut[tok][128]: 16 chunks of 8 u16 per row, chunk' = chunk ^ (tok&15).
    // Write side: 4 lk-rows differ in bits[3:2] of tok -> land in disjoint
    // 4-chunk groups -> 2 lanes/bank (free).
    u16* const sOut = smem;
#pragma unroll
    for (int nf = 0; nf < 4; ++nf) {
        const int col = wn + nf * 16 + lm;     // 0..127 within tile
        const float bb = b1[p * DHID + n0v + col];
        const int cc = col >> 3, c7 = col & 7;
#pragma unroll
        for (int mf = 0; mf < 4; ++mf) {
#pragma unroll
            for (int j = 0; j < 4; ++j) {
                const int tok = wm + mf * 16 + lk * 4 + j;
                float v = acc[mf][nf][j] + bb;
                float g = 0.5f * v * (1.0f + erff(v * 0.70710678118654752f));
                sOut[tok * 128 + ((cc ^ (tok & 15)) * 8) + c7] = f2h_bits(g);
            }
        }
    }
    __syncthreads();
    // coalesced copy-out: 2 threads/row, full 256B row segments
    const int r = tid >> 1, hh = tid & 1;
    if (m0 + r < cnt) {
        u16* dst = hb + (size_t)(off + m0 + r) * DHID + n0v;
#pragma unroll
        for (int c = 0; c < 8; ++c) {
            const int l = hh * 8 + c;
            *(int4*)(dst + l * 8) = *(const int4*)(sOut + r * 128 + ((l ^ (r & 15)) * 8));
        }
    }
}

// ---------------- gemm2: 64x128 tile (more TLP), direct f32 scatter epilogue --
__global__ __launch_bounds__(256, 4) void gemm2_k(
    const u16* __restrict__ hb, const u16* __restrict__ w2b,
    const float* __restrict__ b2, const int* __restrict__ perm,
    const int* __restrict__ offsets, const int* __restrict__ meta,
    const int* __restrict__ t2p, const int* __restrict__ t2m,
    float* __restrict__ out)
{
    __shared__ __align__(16) u16 smem[12288];   // sA 8KB | sB 16KB
    if ((int)blockIdx.y >= meta[1]) return;
    const int p   = t2p[blockIdx.y];
    const int m0  = t2m[blockIdx.y];
    const int off = offsets[p];
    const int cnt = offsets[p + 1] - off;
    const int n0v = blockIdx.x * 128;

    u16* const sA = smem;
    u16* const sB = smem + 4096;

    const int tid = threadIdx.x;
    const u16* aptr[2];
    const u16* bptr[4];
#pragma unroll
    for (int c = 0; c < 2; ++c) {
        const int slot = c * 256 + tid, row = slot >> 3, ch = slot & 7;
        aptr[c] = hb + (size_t)(off + min(m0 + row, cnt - 1)) * DHID + ((ch ^ (row & 7)) * 8);
    }
#pragma unroll
    for (int c = 0; c < 4; ++c) {
        const int slot = c * 256 + tid, row = slot >> 3, ch = slot & 7;
        bptr[c] = w2b + ((size_t)p * DOUT + n0v + row) * DHID + ((ch ^ (row & 7)) * 8);
    }
    const int wave = tid >> 6, lane = tid & 63;
    const int wr = wave >> 1, wc = wave & 1;    // 2x2 wave grid, wave tile 32x64
    const int lm = lane & 15, lk = lane >> 4;

    f32x4 acc[2][4];
#pragma unroll
    for (int a = 0; a < 2; ++a)
#pragma unroll
        for (int b = 0; b < 4; ++b) acc[a][b] = (f32x4){0.f, 0.f, 0.f, 0.f};

    for (int kt = 0; kt < DHID / 64; ++kt) {
        const int k0 = kt * 64;
#pragma unroll
        for (int c = 0; c < 2; ++c) gl_lds16(aptr[c] + k0, sA + c * 2048 + tid * 8);
#pragma unroll
        for (int c = 0; c < 4; ++c) gl_lds16(bptr[c] + k0, sB + c * 2048 + tid * 8);
        __syncthreads();
#pragma unroll
        for (int kk = 0; kk < 2; ++kk) {
            f16x8 af[2], bf[4];
#pragma unroll
            for (int mf = 0; mf < 2; ++mf) {
                const int row = wr * 32 + mf * 16 + lm;
                const int g   = kk * 4 + lk;
                af[mf] = *(const f16x8*)(sA + row * 64 + ((g ^ (row & 7)) * 8));
            }
#pragma unroll
            for (int nf = 0; nf < 4; ++nf) {
                const int row = wc * 64 + nf * 16 + lm;
                const int g   = kk * 4 + lk;
                bf[nf] = *(const f16x8*)(sB + row * 64 + ((g ^ (row & 7)) * 8));
            }
#pragma unroll
            for (int mf = 0; mf < 2; ++mf)
#pragma unroll
                for (int nf = 0; nf < 4; ++nf)
                    acc[mf][nf] = __builtin_amdgcn_mfma_f32_16x16x32_f16(
                        af[mf], bf[nf], acc[mf][nf], 0, 0, 0);
        }
        __syncthreads();
    }

    // epilogue: f32 scatter, 64B full-sector runs per fragment
#pragma unroll
    for (int nf = 0; nf < 4; ++nf) {
        const int col = n0v + wc * 64 + nf * 16 + lm;
        const float bb = b2[p * DOUT + col];
#pragma unroll
        for (int mf = 0; mf < 2; ++mf) {
#pragma unroll
            for (int j = 0; j < 4; ++j) {
                const int tok = wr * 32 + mf * 16 + lk * 4 + j;
                if (m0 + tok < cnt)
                    out[(size_t)perm[off + m0 + tok] * DOUT + col] = acc[mf][nf][j] + bb;
            }
        }
    }
}

// ---------------- launch ----------------
extern "C" void kernel_launch(void* const* d_in, const int* in_sizes, int n_in,
                              void* d_out, int out_size, void* d_ws, size_t ws_size,
                              hipStream_t stream) {
    const float* x    = (const float*)d_in[0];
    const float* W1   = (const float*)d_in[1];
    const float* b1   = (const float*)d_in[2];
    const float* W2   = (const float*)d_in[3];
    const float* b2   = (const float*)d_in[4];
    const int*   pidx = (const int*)d_in[5];
    float*       out  = (float*)d_out;

    char* ws      = (char*)d_ws;
    int* offsets  = (int*)(ws + WS_OFFSETS);
    int* meta     = (int*)(ws + WS_META);
    int* t1p      = (int*)(ws + WS_T1P);
    int* t1m      = (int*)(ws + WS_T1M);
    int* t2p      = (int*)(ws + WS_T2P);
    int* t2m      = (int*)(ws + WS_T2M);
    int* blkhist  = (int*)(ws + WS_BLKHIST);
    int* blkbase  = (int*)(ws + WS_BLKBASE);
    int* perm     = (int*)(ws + WS_PERM);
    u16* xb       = (u16*)(ws + WS_XB);
    u16* w1b      = (u16*)(ws + WS_W1B);
    u16* w2b      = (u16*)(ws + WS_W2B);
    u16* hb       = (u16*)(ws + WS_HB);

    prep_k<<<2048, 256, 0, stream>>>(pidx, x, W1, W2, blkhist, xb, w1b, w2b);
    scan_k<<<1, 64, 0, stream>>>(blkhist, offsets, blkbase, meta, t1p, t1m, t2p, t2m);
    scatter_k<<<NBLK, 256, 0, stream>>>(pidx, blkbase, perm);

    gemm1_k<<<dim3(DHID / 128, 264), 256, 0, stream>>>(
        xb, w1b, b1, perm, offsets, meta, t1p, t1m, hb);
    gemm2_k<<<dim3(DOUT / 128, 520), 256, 0, stream>>>(
        hb, w2b, b2, perm, offsets, meta, t2p, t2m, out);
}

// Round 6
// 115.531 us; speedup vs baseline: 2.0513x; 1.1435x over previous
//
#include <hip/hip_runtime.h>
#include <hip/hip_fp16.h>
#include <cstdint>

#define NT      32768
#define DIN     256
#define DHID    1024
#define DOUT    256
#define NPLANES 8
#define NBLK    (NT / 256)

typedef unsigned short u16;
typedef __attribute__((ext_vector_type(8))) _Float16 f16x8;
typedef __attribute__((ext_vector_type(4))) float    f32x4;

// ---------------- workspace layout (bytes) ----------------
#define WS_OFFSETS 0                           // 9 ints
#define WS_META    64                          // 1 int (ntiles, 64-row granularity)
#define WS_TP      1024                        // 544 ints
#define WS_TM      (WS_TP + 544*4)
#define WS_BLKHIST (WS_TM + 544*4)
#define WS_BLKBASE (WS_BLKHIST + NBLK*8*4)
#define WS_PERM    (WS_BLKBASE + NBLK*8*4)
#define WS_XB      (WS_PERM + NT*4)            // NT*DIN f16, natural order
#define WS_W1B     (WS_XB + NT*DIN*2)
#define WS_W2B     (WS_W1B + NPLANES*DHID*DIN*2)
#define WS_HB      (WS_W2B + NPLANES*DOUT*DHID*2)   // NT*DHID f16, bucketed

__device__ __forceinline__ u16 f2h_bits(float f) {
    __half h = __float2half(f);
    return *reinterpret_cast<u16*>(&h);
}

__device__ __forceinline__ void gl_lds16(const void* g, void* l) {
    __builtin_amdgcn_global_load_lds(
        (const __attribute__((address_space(1))) void*)g,
        (__attribute__((address_space(3))) void*)l,
        16, 0, 0);
}

// ---------------- fused prologue: per-block hist + f32->f16 converts ----------
__global__ void prep_k(const int* __restrict__ pidx, const float* __restrict__ x,
                       const float* __restrict__ W1, const float* __restrict__ W2,
                       int* __restrict__ blkhist, u16* __restrict__ xb,
                       u16* __restrict__ w1b, u16* __restrict__ w2b) {
    __shared__ int cnt[NPLANES];
    const int t = threadIdx.x, lane = t & 63;
    if ((int)blockIdx.x < NBLK) {
        if (t < NPLANES) cnt[t] = 0;
        __syncthreads();
        const int p = pidx[blockIdx.x * 256 + t];
#pragma unroll
        for (int q = 0; q < NPLANES; ++q) {
            unsigned long long m = __ballot(p == q);
            if (p == q && __popcll(m & ((1ULL << lane) - 1)) == 0)
                atomicAdd(&cnt[q], __popcll(m));
        }
        __syncthreads();
        if (t < NPLANES) blkhist[blockIdx.x * NPLANES + t] = cnt[t];
    }
    const int n0 = NT * DIN / 4, n1 = NPLANES * DHID * DIN / 4, n2 = NPLANES * DOUT * DHID / 4;
    const int stride = gridDim.x * blockDim.x;
    for (int i = blockIdx.x * blockDim.x + t; i < n0 + n1 + n2; i += stride) {
        const float4* s; ushort4* d; int j;
        if (i < n0)           { s = (const float4*)x;  d = (ushort4*)xb;  j = i; }
        else if (i < n0 + n1) { s = (const float4*)W1; d = (ushort4*)w1b; j = i - n0; }
        else                  { s = (const float4*)W2; d = (ushort4*)w2b; j = i - n0 - n1; }
        float4 v = s[j];
        ushort4 o;
        o.x = f2h_bits(v.x); o.y = f2h_bits(v.y);
        o.z = f2h_bits(v.z); o.w = f2h_bits(v.w);
        d[j] = o;
    }
}

// ---------------- scan: offsets + 64-row tile list + per-block bases ----------
__global__ void scan_k(const int* __restrict__ blkhist, int* __restrict__ offsets,
                       int* __restrict__ blkbase, int* __restrict__ meta,
                       int* __restrict__ tp, int* __restrict__ tm) {
    __shared__ int tot[NPLANES];
    const int t = threadIdx.x;
    if (t < NPLANES) {
        int s = 0;
#pragma unroll 8
        for (int b = 0; b < NBLK; ++b) s += blkhist[b * NPLANES + t];
        tot[t] = s;
    }
    __syncthreads();
    if (t == 0) {
        int off = 0, tc = 0;
        for (int p = 0; p < NPLANES; ++p) {
            offsets[p] = off;
            for (int m = 0; m < tot[p]; m += 64) { tp[tc] = p; tm[tc] = m; ++tc; }
            off += tot[p];
        }
        offsets[NPLANES] = off;
        meta[0] = tc;
    }
    __syncthreads();
    if (t < NPLANES) {
        int run = offsets[t];
#pragma unroll 8
        for (int b = 0; b < NBLK; ++b) {
            blkbase[b * NPLANES + t] = run;
            run += blkhist[b * NPLANES + t];
        }
    }
}

__global__ void scatter_k(const int* __restrict__ pidx, const int* __restrict__ blkbase,
                          int* __restrict__ perm) {
    __shared__ int wcnt[4][NPLANES];
    __shared__ int wbase[4][NPLANES];
    const int t = threadIdx.x, lane = t & 63, wave = t >> 6;
    const int i = blockIdx.x * 256 + t;
    const int p = pidx[i];
    int rank = 0;
#pragma unroll
    for (int q = 0; q < NPLANES; ++q) {
        unsigned long long m = __ballot(p == q);
        if (lane == 0) wcnt[wave][q] = __popcll(m);
        if (p == q) rank = __popcll(m & ((1ULL << lane) - 1));
    }
    __syncthreads();
    if (t < NPLANES) {
        int run = blkbase[blockIdx.x * NPLANES + t];
#pragma unroll
        for (int w = 0; w < 4; ++w) { wbase[w][t] = run; run += wcnt[w][t]; }
    }
    __syncthreads();
    perm[wbase[wave][p] + rank] = i;
}

// XCD-chunked tile mapping: all NSPLIT n-blocks of a tile on ONE XCD,
// tiles chunked contiguously per XCD (m204 bijective) so W[p] stays L2-hot.
// Assumes HW round-robin: XCD = linear_block_id % 8.
#define XCD_MAP(NSPLIT)                                                        \
    const int ntiles = meta[0];                                                \
    const int xcd = blockIdx.x & 7, idx = blockIdx.x >> 3;                     \
    const int q8 = ntiles >> 3, r8 = ntiles & 7;                               \
    const int tn = q8 + (xcd < r8 ? 1 : 0);                                    \
    if (idx >= tn * (NSPLIT)) return;                                          \
    const int tile = (xcd < r8 ? xcd * (q8 + 1)                                \
                               : r8 * (q8 + 1) + (xcd - r8) * q8)              \
                     + idx / (NSPLIT);                                         \
    const int n0v = (idx % (NSPLIT)) * 128;

// ---------------- gemm1: 64x128 tile, A gathered via perm, LDS-staged epilogue
__global__ __launch_bounds__(256, 4) void gemm1_k(
    const u16* __restrict__ xb, const u16* __restrict__ w1b,
    const float* __restrict__ b1, const int* __restrict__ perm,
    const int* __restrict__ offsets, const int* __restrict__ meta,
    const int* __restrict__ tp, const int* __restrict__ tm,
    u16* __restrict__ hb)
{
    __shared__ __align__(16) u16 smem[12288];   // sA 8KB | sB 16KB; sOut 16KB reuse
    XCD_MAP(8)
    const int p   = tp[tile];
    const int m0  = tm[tile];
    const int off = offsets[p];
    const int cnt = offsets[p + 1] - off;

    u16* const sA = smem;
    u16* const sB = smem + 4096;

    const int tid = threadIdx.x;
    const u16* aptr[2];
    const u16* bptr[4];
#pragma unroll
    for (int c = 0; c < 2; ++c) {
        const int slot = c * 256 + tid, row = slot >> 3, ch = slot & 7;
        const int gr = min(m0 + row, cnt - 1);
        aptr[c] = xb + (size_t)perm[off + gr] * DIN + ((ch ^ (row & 7)) * 8);
    }
#pragma unroll
    for (int c = 0; c < 4; ++c) {
        const int slot = c * 256 + tid, row = slot >> 3, ch = slot & 7;
        bptr[c] = w1b + ((size_t)p * DHID + n0v + row) * DIN + ((ch ^ (row & 7)) * 8);
    }
    const int wave = tid >> 6, lane = tid & 63;
    const int wr = wave >> 1, wc = wave & 1;    // 2x2 waves, wave tile 32x64
    const int lm = lane & 15, lk = lane >> 4;

    f32x4 acc[2][4];
#pragma unroll
    for (int a = 0; a < 2; ++a)
#pragma unroll
        for (int b = 0; b < 4; ++b) acc[a][b] = (f32x4){0.f, 0.f, 0.f, 0.f};

    for (int kt = 0; kt < DIN / 64; ++kt) {
        const int k0 = kt * 64;
#pragma unroll
        for (int c = 0; c < 2; ++c) gl_lds16(aptr[c] + k0, sA + c * 2048 + tid * 8);
#pragma unroll
        for (int c = 0; c < 4; ++c) gl_lds16(bptr[c] + k0, sB + c * 2048 + tid * 8);
        __syncthreads();
#pragma unroll
        for (int kk = 0; kk < 2; ++kk) {
            f16x8 af[2], bf[4];
#pragma unroll
            for (int mf = 0; mf < 2; ++mf) {
                const int row = wr * 32 + mf * 16 + lm;
                const int g   = kk * 4 + lk;
                af[mf] = *(const f16x8*)(sA + row * 64 + ((g ^ (row & 7)) * 8));
            }
#pragma unroll
            for (int nf = 0; nf < 4; ++nf) {
                const int row = wc * 64 + nf * 16 + lm;
                const int g   = kk * 4 + lk;
                bf[nf] = *(const f16x8*)(sB + row * 64 + ((g ^ (row & 7)) * 8));
            }
#pragma unroll
            for (int mf = 0; mf < 2; ++mf)
#pragma unroll
                for (int nf = 0; nf < 4; ++nf)
                    acc[mf][nf] = __builtin_amdgcn_mfma_f32_16x16x32_f16(
                        af[mf], bf[nf], acc[mf][nf], 0, 0, 0);
        }
        __syncthreads();
    }

    // ---- epilogue: gelu -> chunk-swizzled sOut, then coalesced copy-out ----
    u16* const sOut = smem;                     // 64 x 128 u16 = 16KB
#pragma unroll
    for (int nf = 0; nf < 4; ++nf) {
        const int col = wc * 64 + nf * 16 + lm;
        const float bb = b1[p * DHID + n0v + col];
        const int cc = col >> 3, c7 = col & 7;
#pragma unroll
        for (int mf = 0; mf < 2; ++mf) {
#pragma unroll
            for (int j = 0; j < 4; ++j) {
                const int tok = wr * 32 + mf * 16 + lk * 4 + j;
                float v = acc[mf][nf][j] + bb;
                float g = 0.5f * v * (1.0f + erff(v * 0.70710678118654752f));
                sOut[tok * 128 + ((cc ^ (tok & 15)) * 8) + c7] = f2h_bits(g);
            }
        }
    }
    __syncthreads();
    const int r = tid >> 2, qq = tid & 3;       // 4 threads/row, 64B each
    if (m0 + r < cnt) {
        u16* dst = hb + (size_t)(off + m0 + r) * DHID + n0v;
#pragma unroll
        for (int c = 0; c < 4; ++c) {
            const int l = qq * 4 + c;
            *(int4*)(dst + l * 8) = *(const int4*)(sOut + r * 128 + ((l ^ (r & 15)) * 8));
        }
    }
}

// ---------------- gemm2: 64x128 tile, direct f32 scatter epilogue -------------
__global__ __launch_bounds__(256, 4) void gemm2_k(
    const u16* __restrict__ hb, const u16* __restrict__ w2b,
    const float* __restrict__ b2, const int* __restrict__ perm,
    const int* __restrict__ offsets, const int* __restrict__ meta,
    const int* __restrict__ tp, const int* __restrict__ tm,
    float* __restrict__ out)
{
    __shared__ __align__(16) u16 smem[12288];   // sA 8KB | sB 16KB
    XCD_MAP(2)
    const int p   = tp[tile];
    const int m0  = tm[tile];
    const int off = offsets[p];
    const int cnt = offsets[p + 1] - off;

    u16* const sA = smem;
    u16* const sB = smem + 4096;

    const int tid = threadIdx.x;
    const u16* aptr[2];
    const u16* bptr[4];
#pragma unroll
    for (int c = 0; c < 2; ++c) {
        const int slot = c * 256 + tid, row = slot >> 3, ch = slot & 7;
        aptr[c] = hb + (size_t)(off + min(m0 + row, cnt - 1)) * DHID + ((ch ^ (row & 7)) * 8);
    }
#pragma unroll
    for (int c = 0; c < 4; ++c) {
        const int slot = c * 256 + tid, row = slot >> 3, ch = slot & 7;
        bptr[c] = w2b + ((size_t)p * DOUT + n0v + row) * DHID + ((ch ^ (row & 7)) * 8);
    }
    const int wave = tid >> 6, lane = tid & 63;
    const int wr = wave >> 1, wc = wave & 1;
    const int lm = lane & 15, lk = lane >> 4;

    f32x4 acc[2][4];
#pragma unroll
    for (int a = 0; a < 2; ++a)
#pragma unroll
        for (int b = 0; b < 4; ++b) acc[a][b] = (f32x4){0.f, 0.f, 0.f, 0.f};

    for (int kt = 0; kt < DHID / 64; ++kt) {
        const int k0 = kt * 64;
#pragma unroll
        for (int c = 0; c < 2; ++c) gl_lds16(aptr[c] + k0, sA + c * 2048 + tid * 8);
#pragma unroll
        for (int c = 0; c < 4; ++c) gl_lds16(bptr[c] + k0, sB + c * 2048 + tid * 8);
        __syncthreads();
#pragma unroll
        for (int kk = 0; kk < 2; ++kk) {
            f16x8 af[2], bf[4];
#pragma unroll
            for (int mf = 0; mf < 2; ++mf) {
                const int row = wr * 32 + mf * 16 + lm;
                const int g   = kk * 4 + lk;
                af[mf] = *(const f16x8*)(sA + row * 64 + ((g ^ (row & 7)) * 8));
            }
#pragma unroll
            for (int nf = 0; nf < 4; ++nf) {
                const int row = wc * 64 + nf * 16 + lm;
                const int g   = kk * 4 + lk;
                bf[nf] = *(const f16x8*)(sB + row * 64 + ((g ^ (row & 7)) * 8));
            }
#pragma unroll
            for (int mf = 0; mf < 2; ++mf)
#pragma unroll
                for (int nf = 0; nf < 4; ++nf)
                    acc[mf][nf] = __builtin_amdgcn_mfma_f32_16x16x32_f16(
                        af[mf], bf[nf], acc[mf][nf], 0, 0, 0);
        }
        __syncthreads();
    }

#pragma unroll
    for (int nf = 0; nf < 4; ++nf) {
        const int col = n0v + wc * 64 + nf * 16 + lm;
        const float bb = b2[p * DOUT + col];
#pragma unroll
        for (int mf = 0; mf < 2; ++mf) {
#pragma unroll
            for (int j = 0; j < 4; ++j) {
                const int tok = wr * 32 + mf * 16 + lk * 4 + j;
                if (m0 + tok < cnt)
                    out[(size_t)perm[off + m0 + tok] * DOUT + col] = acc[mf][nf][j] + bb;
            }
        }
    }
}

// ---------------- launch ----------------
extern "C" void kernel_launch(void* const* d_in, const int* in_sizes, int n_in,
                              void* d_out, int out_size, void* d_ws, size_t ws_size,
                              hipStream_t stream) {
    const float* x    = (const float*)d_in[0];
    const float* W1   = (const float*)d_in[1];
    const float* b1   = (const float*)d_in[2];
    const float* W2   = (const float*)d_in[3];
    const float* b2   = (const float*)d_in[4];
    const int*   pidx = (const int*)d_in[5];
    float*       out  = (float*)d_out;

    char* ws      = (char*)d_ws;
    int* offsets  = (int*)(ws + WS_OFFSETS);
    int* meta     = (int*)(ws + WS_META);
    int* tp       = (int*)(ws + WS_TP);
    int* tm       = (int*)(ws + WS_TM);
    int* blkhist  = (int*)(ws + WS_BLKHIST);
    int* blkbase  = (int*)(ws + WS_BLKBASE);
    int* perm     = (int*)(ws + WS_PERM);
    u16* xb       = (u16*)(ws + WS_XB);
    u16* w1b      = (u16*)(ws + WS_W1B);
    u16* w2b      = (u16*)(ws + WS_W2B);
    u16* hb       = (u16*)(ws + WS_HB);

    prep_k<<<2048, 256, 0, stream>>>(pidx, x, W1, W2, blkhist, xb, w1b, w2b);
    scan_k<<<1, 64, 0, stream>>>(blkhist, offsets, blkbase, meta, tp, tm);
    scatter_k<<<NBLK, 256, 0, stream>>>(pidx, blkbase, perm);

    // gemm1: 8 n-blocks/tile, <=66 tiles/xcd -> 8*66*8 = 4224 slots
    gemm1_k<<<4224, 256, 0, stream>>>(xb, w1b, b1, perm, offsets, meta, tp, tm, hb);
    // gemm2: 2 n-blocks/tile -> 8*66*2 = 1056 slots
    gemm2_k<<<1056, 256, 0, stream>>>(hb, w2b, b2, perm, offsets, meta, tp, tm, out);
}

// Round 7
// 115.093 us; speedup vs baseline: 2.0591x; 1.0038x over previous
//
#include <hip/hip_runtime.h>
#include <hip/hip_fp16.h>
#include <cstdint>

#define NT      32768
#define DIN     256
#define DHID    1024
#define DOUT    256
#define NPLANES 8
#define NBLK    (NT / 256)

typedef unsigned short u16;
typedef __attribute__((ext_vector_type(8))) _Float16 f16x8;
typedef __attribute__((ext_vector_type(4))) float    f32x4;

// ---------------- workspace layout (bytes) ----------------
#define WS_OFFSETS 0                           // 9 ints
#define WS_META    64                          // 1 int (ntiles, 64-row granularity)
#define WS_TP      1024                        // 544 ints
#define WS_TM      (WS_TP + 544*4)
#define WS_BLKHIST (WS_TM + 544*4)
#define WS_BLKBASE (WS_BLKHIST + NBLK*8*4)
#define WS_PERM    (WS_BLKBASE + NBLK*8*4)
#define WS_XB      (WS_PERM + NT*4)            // NT*DIN f16, natural order
#define WS_W1B     (WS_XB + NT*DIN*2)
#define WS_W2B     (WS_W1B + NPLANES*DHID*DIN*2)
#define WS_HB      (WS_W2B + NPLANES*DOUT*DHID*2)   // NT*DHID f16, bucketed

__device__ __forceinline__ u16 f2h_bits(float f) {
    __half h = __float2half(f);
    return *reinterpret_cast<u16*>(&h);
}

__device__ __forceinline__ void gl_lds16(const void* g, void* l) {
    __builtin_amdgcn_global_load_lds(
        (const __attribute__((address_space(1))) void*)g,
        (__attribute__((address_space(3))) void*)l,
        16, 0, 0);
}

// fast gelu: tanh-form, |dev vs exact erf-gelu| <~ 5e-4 (negligible after W2)
// ~8 VALU ops vs erff's ~25-30.
__device__ __forceinline__ float gelu_fast(float x) {
    const float u = x * (1.5957691216f + 0.07135481283f * x * x);
    const float e = __expf(-u);
    return x * __builtin_amdgcn_rcpf(1.0f + e);
}

// ---------------- fused prologue: per-block hist + f32->f16 converts ----------
__global__ void prep_k(const int* __restrict__ pidx, const float* __restrict__ x,
                       const float* __restrict__ W1, const float* __restrict__ W2,
                       int* __restrict__ blkhist, u16* __restrict__ xb,
                       u16* __restrict__ w1b, u16* __restrict__ w2b) {
    __shared__ int cnt[NPLANES];
    const int t = threadIdx.x, lane = t & 63;
    if ((int)blockIdx.x < NBLK) {
        if (t < NPLANES) cnt[t] = 0;
        __syncthreads();
        const int p = pidx[blockIdx.x * 256 + t];
#pragma unroll
        for (int q = 0; q < NPLANES; ++q) {
            unsigned long long m = __ballot(p == q);
            if (p == q && __popcll(m & ((1ULL << lane) - 1)) == 0)
                atomicAdd(&cnt[q], __popcll(m));
        }
        __syncthreads();
        if (t < NPLANES) blkhist[blockIdx.x * NPLANES + t] = cnt[t];
    }
    const int n0 = NT * DIN / 4, n1 = NPLANES * DHID * DIN / 4, n2 = NPLANES * DOUT * DHID / 4;
    const int stride = gridDim.x * blockDim.x;
    for (int i = blockIdx.x * blockDim.x + t; i < n0 + n1 + n2; i += stride) {
        const float4* s; ushort4* d; int j;
        if (i < n0)           { s = (const float4*)x;  d = (ushort4*)xb;  j = i; }
        else if (i < n0 + n1) { s = (const float4*)W1; d = (ushort4*)w1b; j = i - n0; }
        else                  { s = (const float4*)W2; d = (ushort4*)w2b; j = i - n0 - n1; }
        float4 v = s[j];
        ushort4 o;
        o.x = f2h_bits(v.x); o.y = f2h_bits(v.y);
        o.z = f2h_bits(v.z); o.w = f2h_bits(v.w);
        d[j] = o;
    }
}

// ---------------- scan: offsets + 64-row tile list + per-block bases ----------
__global__ void scan_k(const int* __restrict__ blkhist, int* __restrict__ offsets,
                       int* __restrict__ blkbase, int* __restrict__ meta,
                       int* __restrict__ tp, int* __restrict__ tm) {
    __shared__ int tot[NPLANES];
    const int t = threadIdx.x;
    if (t < NPLANES) {
        int s = 0;
#pragma unroll 8
        for (int b = 0; b < NBLK; ++b) s += blkhist[b * NPLANES + t];
        tot[t] = s;
    }
    __syncthreads();
    if (t == 0) {
        int off = 0, tc = 0;
        for (int p = 0; p < NPLANES; ++p) {
            offsets[p] = off;
            for (int m = 0; m < tot[p]; m += 64) { tp[tc] = p; tm[tc] = m; ++tc; }
            off += tot[p];
        }
        offsets[NPLANES] = off;
        meta[0] = tc;
    }
    __syncthreads();
    if (t < NPLANES) {
        int run = offsets[t];
#pragma unroll 8
        for (int b = 0; b < NBLK; ++b) {
            blkbase[b * NPLANES + t] = run;
            run += blkhist[b * NPLANES + t];
        }
    }
}

__global__ void scatter_k(const int* __restrict__ pidx, const int* __restrict__ blkbase,
                          int* __restrict__ perm) {
    __shared__ int wcnt[4][NPLANES];
    __shared__ int wbase[4][NPLANES];
    const int t = threadIdx.x, lane = t & 63, wave = t >> 6;
    const int i = blockIdx.x * 256 + t;
    const int p = pidx[i];
    int rank = 0;
#pragma unroll
    for (int q = 0; q < NPLANES; ++q) {
        unsigned long long m = __ballot(p == q);
        if (lane == 0) wcnt[wave][q] = __popcll(m);
        if (p == q) rank = __popcll(m & ((1ULL << lane) - 1));
    }
    __syncthreads();
    if (t < NPLANES) {
        int run = blkbase[blockIdx.x * NPLANES + t];
#pragma unroll
        for (int w = 0; w < 4; ++w) { wbase[w][t] = run; run += wcnt[w][t]; }
    }
    __syncthreads();
    perm[wbase[wave][p] + rank] = i;
}

// XCD-chunked tile mapping: all NSPLIT n-blocks of a tile on ONE XCD,
// tiles chunked contiguously per XCD (m204 bijective) so W[p] stays L2-hot.
// VERIFIED R6: HW round-robin XCD = linear_block_id % 8 (FETCH 68.6->11.1 MB).
#define XCD_MAP(NSPLIT)                                                        \
    const int ntiles = meta[0];                                                \
    const int xcd = blockIdx.x & 7, idx = blockIdx.x >> 3;                     \
    const int q8 = ntiles >> 3, r8 = ntiles & 7;                               \
    const int tn = q8 + (xcd < r8 ? 1 : 0);                                    \
    if (idx >= tn * (NSPLIT)) return;                                          \
    const int tile = (xcd < r8 ? xcd * (q8 + 1)                                \
                               : r8 * (q8 + 1) + (xcd - r8) * q8)              \
                     + idx / (NSPLIT);                                         \
    const int n0v = (idx % (NSPLIT)) * 128;

// ---------------- gemm1: 64x128 tile, A gathered via perm, LDS-staged epilogue
__global__ __launch_bounds__(256, 6) void gemm1_k(
    const u16* __restrict__ xb, const u16* __restrict__ w1b,
    const float* __restrict__ b1, const int* __restrict__ perm,
    const int* __restrict__ offsets, const int* __restrict__ meta,
    const int* __restrict__ tp, const int* __restrict__ tm,
    u16* __restrict__ hb)
{
    __shared__ __align__(16) u16 smem[12288];   // sA 8KB | sB 16KB; sOut 16KB reuse
    XCD_MAP(8)
    const int p   = tp[tile];
    const int m0  = tm[tile];
    const int off = offsets[p];
    const int cnt = offsets[p + 1] - off;

    u16* const sA = smem;
    u16* const sB = smem + 4096;

    const int tid = threadIdx.x;
    const u16* aptr[2];
    const u16* bptr[4];
#pragma unroll
    for (int c = 0; c < 2; ++c) {
        const int slot = c * 256 + tid, row = slot >> 3, ch = slot & 7;
        const int gr = min(m0 + row, cnt - 1);
        aptr[c] = xb + (size_t)perm[off + gr] * DIN + ((ch ^ (row & 7)) * 8);
    }
#pragma unroll
    for (int c = 0; c < 4; ++c) {
        const int slot = c * 256 + tid, row = slot >> 3, ch = slot & 7;
        bptr[c] = w1b + ((size_t)p * DHID + n0v + row) * DIN + ((ch ^ (row & 7)) * 8);
    }
    const int wave = tid >> 6, lane = tid & 63;
    const int wr = wave >> 1, wc = wave & 1;    // 2x2 waves, wave tile 32x64
    const int lm = lane & 15, lk = lane >> 4;

    f32x4 acc[2][4];
#pragma unroll
    for (int a = 0; a < 2; ++a)
#pragma unroll
        for (int b = 0; b < 4; ++b) acc[a][b] = (f32x4){0.f, 0.f, 0.f, 0.f};

    for (int kt = 0; kt < DIN / 64; ++kt) {
        const int k0 = kt * 64;
#pragma unroll
        for (int c = 0; c < 2; ++c) gl_lds16(aptr[c] + k0, sA + c * 2048 + tid * 8);
#pragma unroll
        for (int c = 0; c < 4; ++c) gl_lds16(bptr[c] + k0, sB + c * 2048 + tid * 8);
        __syncthreads();
#pragma unroll
        for (int kk = 0; kk < 2; ++kk) {
            f16x8 af[2], bf[4];
#pragma unroll
            for (int mf = 0; mf < 2; ++mf) {
                const int row = wr * 32 + mf * 16 + lm;
                const int g   = kk * 4 + lk;
                af[mf] = *(const f16x8*)(sA + row * 64 + ((g ^ (row & 7)) * 8));
            }
#pragma unroll
            for (int nf = 0; nf < 4; ++nf) {
                const int row = wc * 64 + nf * 16 + lm;
                const int g   = kk * 4 + lk;
                bf[nf] = *(const f16x8*)(sB + row * 64 + ((g ^ (row & 7)) * 8));
            }
#pragma unroll
            for (int mf = 0; mf < 2; ++mf)
#pragma unroll
                for (int nf = 0; nf < 4; ++nf)
                    acc[mf][nf] = __builtin_amdgcn_mfma_f32_16x16x32_f16(
                        af[mf], bf[nf], acc[mf][nf], 0, 0, 0);
        }
        __syncthreads();
    }

    // ---- epilogue: fast gelu -> chunk-swizzled sOut, then coalesced copy-out ----
    u16* const sOut = smem;                     // 64 x 128 u16 = 16KB
#pragma unroll
    for (int nf = 0; nf < 4; ++nf) {
        const int col = wc * 64 + nf * 16 + lm;
        const float bb = b1[p * DHID + n0v + col];
        const int cc = col >> 3, c7 = col & 7;
#pragma unroll
        for (int mf = 0; mf < 2; ++mf) {
#pragma unroll
            for (int j = 0; j < 4; ++j) {
                const int tok = wr * 32 + mf * 16 + lk * 4 + j;
                sOut[tok * 128 + ((cc ^ (tok & 15)) * 8) + c7] =
                    f2h_bits(gelu_fast(acc[mf][nf][j] + bb));
            }
        }
    }
    __syncthreads();
    const int r = tid >> 2, qq = tid & 3;       // 4 threads/row, 64B each
    if (m0 + r < cnt) {
        u16* dst = hb + (size_t)(off + m0 + r) * DHID + n0v;
#pragma unroll
        for (int c = 0; c < 4; ++c) {
            const int l = qq * 4 + c;
            *(int4*)(dst + l * 8) = *(const int4*)(sOut + r * 128 + ((l ^ (r & 15)) * 8));
        }
    }
}

// ---------------- gemm2: 64x128 tile, counted-vmcnt double-buffered ----------
// T4 pattern: next tile's global_load_lds stay in flight across the barrier;
// only wait vmcnt(6) (own prev-tile loads done), never drain to 0 mid-loop.
__global__ __launch_bounds__(256, 3) void gemm2_k(
    const u16* __restrict__ hb, const u16* __restrict__ w2b,
    const float* __restrict__ b2, const int* __restrict__ perm,
    const int* __restrict__ offsets, const int* __restrict__ meta,
    const int* __restrict__ tp, const int* __restrict__ tm,
    float* __restrict__ out)
{
    __shared__ __align__(16) u16 smem[2][12288];   // per buf: sA 8KB | sB 16KB
    XCD_MAP(2)
    const int p   = tp[tile];
    const int m0  = tm[tile];
    const int off = offsets[p];
    const int cnt = offsets[p + 1] - off;

    const int tid = threadIdx.x;
    const u16* aptr[2];
    const u16* bptr[4];
#pragma unroll
    for (int c = 0; c < 2; ++c) {
        const int slot = c * 256 + tid, row = slot >> 3, ch = slot & 7;
        aptr[c] = hb + (size_t)(off + min(m0 + row, cnt - 1)) * DHID + ((ch ^ (row & 7)) * 8);
    }
#pragma unroll
    for (int c = 0; c < 4; ++c) {
        const int slot = c * 256 + tid, row = slot >> 3, ch = slot & 7;
        bptr[c] = w2b + ((size_t)p * DOUT + n0v + row) * DHID + ((ch ^ (row & 7)) * 8);
    }
    const int wave = tid >> 6, lane = tid & 63;
    const int wr = wave >> 1, wc = wave & 1;
    const int lm = lane & 15, lk = lane >> 4;

    f32x4 acc[2][4];
#pragma unroll
    for (int a = 0; a < 2; ++a)
#pragma unroll
        for (int b = 0; b < 4; ++b) acc[a][b] = (f32x4){0.f, 0.f, 0.f, 0.f};

#define STAGE2(dst, k0)                                                        \
    do {                                                                       \
        gl_lds16(aptr[0] + (k0), (dst) + tid * 8);                             \
        gl_lds16(aptr[1] + (k0), (dst) + 2048 + tid * 8);                      \
        gl_lds16(bptr[0] + (k0), (dst) + 4096 + tid * 8);                      \
        gl_lds16(bptr[1] + (k0), (dst) + 6144 + tid * 8);                      \
        gl_lds16(bptr[2] + (k0), (dst) + 8192 + tid * 8);                      \
        gl_lds16(bptr[3] + (k0), (dst) + 10240 + tid * 8);                     \
    } while (0)

    // prologue: stage tile 0, full drain
    STAGE2(&smem[0][0], 0);
    asm volatile("s_waitcnt vmcnt(0)" ::: "memory");
    __builtin_amdgcn_s_barrier();

    constexpr int KT = DHID / 64;
    for (int kt = 0; kt < KT; ++kt) {
        const int cur = kt & 1;
        u16* const bufc = &smem[cur][0];
        if (kt + 1 < KT) {
            STAGE2(&smem[cur ^ 1][0], (kt + 1) * 64);
            // own prev-tile (6 oldest) loads complete; next-tile 6 stay in flight
            asm volatile("s_waitcnt vmcnt(6)" ::: "memory");
        } else {
            asm volatile("s_waitcnt vmcnt(0)" ::: "memory");
        }
        __builtin_amdgcn_s_barrier();   // all waves' tile-kt LDS writes visible
#pragma unroll
        for (int kk = 0; kk < 2; ++kk) {
            f16x8 af[2], bf[4];
#pragma unroll
            for (int mf = 0; mf < 2; ++mf) {
                const int row = wr * 32 + mf * 16 + lm;
                const int g   = kk * 4 + lk;
                af[mf] = *(const f16x8*)(bufc + row * 64 + ((g ^ (row & 7)) * 8));
            }
#pragma unroll
            for (int nf = 0; nf < 4; ++nf) {
                const int row = wc * 64 + nf * 16 + lm;
                const int g   = kk * 4 + lk;
                bf[nf] = *(const f16x8*)(bufc + 4096 + row * 64 + ((g ^ (row & 7)) * 8));
            }
#pragma unroll
            for (int mf = 0; mf < 2; ++mf)
#pragma unroll
                for (int nf = 0; nf < 4; ++nf)
                    acc[mf][nf] = __builtin_amdgcn_mfma_f32_16x16x32_f16(
                        af[mf], bf[nf], acc[mf][nf], 0, 0, 0);
        }
        // readers of bufc done before next iteration's STAGE2 overwrites it
        __builtin_amdgcn_s_barrier();
    }
#undef STAGE2

#pragma unroll
    for (int nf = 0; nf < 4; ++nf) {
        const int col = n0v + wc * 64 + nf * 16 + lm;
        const float bb = b2[p * DOUT + col];
#pragma unroll
        for (int mf = 0; mf < 2; ++mf) {
#pragma unroll
            for (int j = 0; j < 4; ++j) {
                const int tok = wr * 32 + mf * 16 + lk * 4 + j;
                if (m0 + tok < cnt)
                    out[(size_t)perm[off + m0 + tok] * DOUT + col] = acc[mf][nf][j] + bb;
            }
        }
    }
}

// ---------------- launch ----------------
extern "C" void kernel_launch(void* const* d_in, const int* in_sizes, int n_in,
                              void* d_out, int out_size, void* d_ws, size_t ws_size,
                              hipStream_t stream) {
    const float* x    = (const float*)d_in[0];
    const float* W1   = (const float*)d_in[1];
    const float* b1   = (const float*)d_in[2];
    const float* W2   = (const float*)d_in[3];
    const float* b2   = (const float*)d_in[4];
    const int*   pidx = (const int*)d_in[5];
    float*       out  = (float*)d_out;

    char* ws      = (char*)d_ws;
    int* offsets  = (int*)(ws + WS_OFFSETS);
    int* meta     = (int*)(ws + WS_META);
    int* tp       = (int*)(ws + WS_TP);
    int* tm       = (int*)(ws + WS_TM);
    int* blkhist  = (int*)(ws + WS_BLKHIST);
    int* blkbase  = (int*)(ws + WS_BLKBASE);
    int* perm     = (int*)(ws + WS_PERM);
    u16* xb       = (u16*)(ws + WS_XB);
    u16* w1b      = (u16*)(ws + WS_W1B);
    u16* w2b      = (u16*)(ws + WS_W2B);
    u16* hb       = (u16*)(ws + WS_HB);

    prep_k<<<2048, 256, 0, stream>>>(pidx, x, W1, W2, blkhist, xb, w1b, w2b);
    scan_k<<<1, 64, 0, stream>>>(blkhist, offsets, blkbase, meta, tp, tm);
    scatter_k<<<NBLK, 256, 0, stream>>>(pidx, blkbase, perm);

    // gemm1: 8 n-blocks/tile, <=66 tiles/xcd -> 8*66*8 = 4224 slots
    gemm1_k<<<4224, 256, 0, stream>>>(xb, w1b, b1, perm, offsets, meta, tp, tm, hb);
    // gemm2: 2 n-blocks/tile -> 8*66*2 = 1056 slots
    gemm2_k<<<1056, 256, 0, stream>>>(hb, w2b, b2, perm, offsets, meta, tp, tm, out);
}